// Round 5
// baseline (395.713 us; speedup 1.0000x reference)
//
#include <hip/hip_runtime.h>
#include <math.h>

#define B_ 64
#define P_ 8732
#define M_ 16
#define C_ 81
#define THRESH 0.5f
#define EPS_ 1e-7f

#define AB_ 64                                  // assign blocks (one per batch)
#define ROWS_PER_CHUNK 64
#define NCHUNKS ((B_ * P_) / ROWS_PER_CHUNK)    // 8732
#define CHUNK_F4 (ROWS_PER_CHUNK * C_ / 4)      // 1296 = 5*256 + 16

// ---------------------------------------------------------------------------
// Kernel 1 (fused): blocks 0..63 = per-batch prior assignment (LDS-lite,
// two-pass, VALU-only -> hides under the BW-bound CE stream on other blocks);
// blocks 64.. = CE log-sum-exp per 64-row chunk (DMA staging, t-independent).
// No data flows between the two roles inside this launch.
// ---------------------------------------------------------------------------
__global__ __launch_bounds__(256, 4) void fused_assign_lse(
    const float* __restrict__ scores,   // [B,P,C]
    const float* __restrict__ boxes,    // [B,M,4] corner
    const int*   __restrict__ labels,   // [B,M]
    const float* __restrict__ priors,   // [P,4] cxcy
    float*       __restrict__ lse,      // [B*P]
    int*         __restrict__ tcls,     // [B*P]
    int*         __restrict__ done_ctr) // [1]
{
    // ---- shared (union across roles; total ~22 KB -> 7 blocks/CU by LDS) ----
    __shared__ __attribute__((aligned(16))) float s_buf[ROWS_PER_CHUNK * C_]; // CE
    __shared__ float s_bx[M_][4];
    __shared__ float s_barea[M_];
    __shared__ int   s_lab[M_];
    __shared__ float s_wv4[M_][4];
    __shared__ int   s_wp4[M_][4];
    __shared__ int   s_tp[M_];
    __shared__ int   s_tn;

    const int tid  = threadIdx.x;
    const int lane = tid & 63;
    const int wv   = tid >> 6;                  // 4 waves

    if (blockIdx.x < AB_) {
        // =================== assign role (batch b) ===================
        const int b = blockIdx.x;
        if (b == 0 && tid == 0) *done_ctr = 0;  // for topk's last-block finalize

        if (tid < M_*4) ((float*)s_bx)[tid] = boxes[b*M_*4 + tid];
        if (tid < M_)   s_lab[tid] = labels[b*M_ + tid];
        __syncthreads();
        if (tid < M_)
            s_barea[tid] = (s_bx[tid][2]-s_bx[tid][0])*(s_bx[tid][3]-s_bx[tid][1]);
        __syncthreads();

        const float4* pri4 = (const float4*)priors;

        // ---- pass 1: per-object best prior (argmax over p, first-p wins) ----
        float bestv[M_]; int bestp[M_];
        #pragma unroll
        for (int m = 0; m < M_; ++m) { bestv[m] = -1.0f; bestp[m] = 0x7fffffff; }

        for (int p = tid; p < P_; p += 256) {
            float4 pc = pri4[p];
            float px1 = pc.x - pc.z*0.5f, py1 = pc.y - pc.w*0.5f;
            float px2 = pc.x + pc.z*0.5f, py2 = pc.y + pc.w*0.5f;
            float parea = (px2-px1)*(py2-py1);
            #pragma unroll
            for (int m = 0; m < M_; ++m) {
                float ix1 = fmaxf(s_bx[m][0], px1);
                float iy1 = fmaxf(s_bx[m][1], py1);
                float ix2 = fminf(s_bx[m][2], px2);
                float iy2 = fminf(s_bx[m][3], py2);
                float iw = fmaxf(ix2-ix1, 0.0f);
                float ih = fmaxf(iy2-iy1, 0.0f);
                float inter = iw*ih;
                float iou = inter / (s_barea[m] + parea - inter); // jaccard: no eps
                if (iou > bestv[m]) { bestv[m] = iou; bestp[m] = p; } // first p wins
            }
        }

        #pragma unroll
        for (int m = 0; m < M_; ++m) {
            float v = bestv[m]; int p = bestp[m];
            #pragma unroll
            for (int o = 32; o; o >>= 1) {
                float v2 = __shfl_xor(v, o);
                int   p2 = __shfl_xor(p, o);
                if (v2 > v || (v2 == v && p2 < p)) { v = v2; p = p2; }
            }
            if (lane == 0) { s_wv4[m][wv] = v; s_wp4[m][wv] = p; }
        }
        __syncthreads();

        // ---- serial: final reduce + faithful filtered-index override table ----
        if (tid == 0) {
            int cnt = 0;
            for (int m = 0; m < M_; ++m) {
                float v = s_wv4[m][0]; int p = s_wp4[m][0];
                #pragma unroll
                for (int w = 1; w < 4; ++w) {
                    float v2 = s_wv4[m][w]; int p2 = s_wp4[m][w];
                    if (v2 > v || (v2 == v && p2 < p)) { v = v2; p = p2; }
                }
                if (v > 0.0f) { s_tp[cnt] = p; cnt++; }  // entry e -> obj idx e
            }
            s_tn = cnt;
        }
        __syncthreads();

        const int tn = s_tn;

        // ---- pass 2: per-prior best (bitwise-identical recompute) + override ----
        for (int p = tid; p < P_; p += 256) {
            float4 pc = pri4[p];
            float px1 = pc.x - pc.z*0.5f, py1 = pc.y - pc.w*0.5f;
            float px2 = pc.x + pc.z*0.5f, py2 = pc.y + pc.w*0.5f;
            float parea = (px2-px1)*(py2-py1);
            float bv = -1.0f; int bm = 0;
            #pragma unroll
            for (int m = 0; m < M_; ++m) {
                float ix1 = fmaxf(s_bx[m][0], px1);
                float iy1 = fmaxf(s_bx[m][1], py1);
                float ix2 = fminf(s_bx[m][2], px2);
                float iy2 = fminf(s_bx[m][3], py2);
                float iw = fmaxf(ix2-ix1, 0.0f);
                float ih = fmaxf(iy2-iy1, 0.0f);
                float inter = iw*ih;
                float iou = inter / (s_barea[m] + parea - inter);
                if (iou > bv) { bv = iou; bm = m; }       // first-max (m asc)
            }
            int ovr = -1;
            for (int e = 0; e < tn; ++e)
                if (s_tp[e] == p) ovr = e;                // last valid m wins
            int tc = (ovr >= 0) ? s_lab[ovr]              // ovl forced to 1.0
                                : ((bv < THRESH) ? 0 : s_lab[bm]);
            tcls[(size_t)b*P_ + p] = tc;
        }
    } else {
        // =================== CE-LSE role (chunk c) ===================
        const int c  = blockIdx.x - AB_;
        const int s  = lane & 3;                // sub-lane within row quad
        const int rl = (lane >> 2) + wv * 16;   // row within chunk, 0..63

        const float4* src4 = (const float4*)scores + (size_t)c * CHUNK_F4;
        float4*       dst4 = (float4*)s_buf;

        #pragma unroll
        for (int k = 0; k < 5; ++k) {
            __builtin_amdgcn_global_load_lds(
                (const __attribute__((address_space(1))) void*)(src4 + k*256 + tid),
                (__attribute__((address_space(3))) void*)(dst4 + k*256 + wv*64),
                16, 0, 0);
        }
        if (tid < 16) dst4[1280 + tid] = src4[1280 + tid];  // 16-f4 tail
        __syncthreads();                                    // drains vmcnt

        const int cnt   = (s == 0) ? 21 : 20;
        const int cbase = (s == 0) ? 0  : (1 + 20 * s);     // 0,21,41,61

        const float* rowp = &s_buf[rl * C_ + cbase];
        float x[21];
        float mx = -INFINITY;
        #pragma unroll
        for (int k = 0; k < 21; ++k) {
            if (k < cnt) { x[k] = rowp[k]; mx = fmaxf(mx, x[k]); }
            else x[k] = -INFINITY;
        }
        mx = fmaxf(mx, __shfl_xor(mx, 1));
        mx = fmaxf(mx, __shfl_xor(mx, 2));

        float e = 0.f;
        #pragma unroll
        for (int k = 0; k < 21; ++k) e += __expf(x[k] - mx);  // exp(-inf)=0 pad
        e += __shfl_xor(e, 1);
        e += __shfl_xor(e, 2);

        if (s == 0)
            lse[(size_t)c * ROWS_PER_CHUNK + rl] = mx + __logf(e);
    }
}

// ---------------------------------------------------------------------------
// Kernel 2: per-batch conf reconstruction (lse - gathered x[t]) + positives
// accounting + exact top-k radix select + last-block scalar finalize.
// ---------------------------------------------------------------------------
__global__ __launch_bounds__(1024) void topk_kernel(
    const float* __restrict__ scores,   // [B,P,C]
    const float* __restrict__ locs,     // [B,P,4]
    const float* __restrict__ lse,      // [B*P]
    const int*   __restrict__ tcls,     // [B*P]
    float*       __restrict__ hard,     // [B]
    float*       __restrict__ psum,     // [B]
    float*       __restrict__ lsum,     // [B]
    int*         __restrict__ npos,     // [B]
    int*         __restrict__ done_ctr, // [1]
    float*       __restrict__ out)      // [1]
{
    const int b = blockIdx.x;
    const int tid = threadIdx.x;
    const int lane = tid & 63;
    const int wv = tid >> 6;

    __shared__ float s_v[P_];           // 34928 B
    __shared__ int   s_hist[16][256];   // 16384 B
    __shared__ int   s_cg[257];
    __shared__ int   s_sel;
    __shared__ int   s_ct[16];
    __shared__ float s_pa[16];
    __shared__ float s_la[16];
    __shared__ int   s_rt[16];
    __shared__ float s_rf[16];
    __shared__ int   s_last;

    const size_t base = (size_t)b * P_;

    // ---- load pass: conf = lse - x[t]; build s_v; count/sum positives ----
    float p_acc = 0.f, l_acc = 0.f; int cpos = 0;
    for (int i = tid; i < P_; i += 1024) {
        const int t = tcls[base + i];
        const float conf = lse[base + i] - scores[(base + i) * C_ + t];
        float v;
        if (t > 0) {
            v = 0.f;
            cpos++;
            p_acc += conf;
            // DIoU(box, box): inter_diag == 0; enclosing box == box
            float4 bx = ((const float4*)locs)[base + i];
            float w = bx.z - bx.x, h = bx.w - bx.y;
            float iw = fmaxf(w, 0.f), ih = fmaxf(h, 0.f);
            float inter = iw * ih;
            float area  = w * h;
            float iou   = inter / (area + area - inter + EPS_);
            float diou  = fminf(fmaxf(iou, -1.f), 1.f);
            l_acc += 1.f - diou;
        } else {
            v = fmaxf(conf, 0.f);       // order-monotonic float bits
        }
        s_v[i] = v;
    }

    #pragma unroll
    for (int o = 32; o; o >>= 1) {
        cpos  += __shfl_xor(cpos, o);
        p_acc += __shfl_xor(p_acc, o);
        l_acc += __shfl_xor(l_acc, o);
    }
    if (lane == 0) { s_ct[wv] = cpos; s_pa[wv] = p_acc; s_la[wv] = l_acc; }
    __syncthreads();                    // also covers s_v

    int cp_tot = 0;
    #pragma unroll
    for (int w = 0; w < 16; ++w) cp_tot += s_ct[w];   // uniform across block
    int k = 3 * cp_tot;
    if (k > P_) k = P_;

    float hsum = 0.f;                   // tid 0's value is the one that counts
    if (k > 0) {                        // block-uniform branch
        const unsigned masks[4]  = {0u, 0xFF800000u, 0xFFFF8000u, 0xFFFFFF80u};
        const int      shifts[4] = {23, 15, 7, 0};

        unsigned prefix = 0u;
        int k_rem = k;

        for (int rd = 0; rd < 4; ++rd) {
            const unsigned hm = masks[rd];
            const int sh = shifts[rd];

            ((int*)s_hist)[tid] = 0;
            ((int*)s_hist)[tid + 1024] = 0;
            ((int*)s_hist)[tid + 2048] = 0;
            ((int*)s_hist)[tid + 3072] = 0;
            __syncthreads();

            for (int i = tid; i < P_; i += 1024) {
                unsigned u = __float_as_uint(s_v[i]);
                if ((u & hm) == prefix)
                    atomicAdd(&s_hist[wv][(u >> sh) & 0xFF], 1);
            }
            __syncthreads();

            if (wv == 0) {
                int carry = 0;
                for (int cbin = 3; cbin >= 0; --cbin) {
                    int bin = cbin * 64 + lane;
                    int tot = 0;
                    #pragma unroll
                    for (int w = 0; w < 16; ++w) tot += s_hist[w][bin];
                    #pragma unroll
                    for (int o = 1; o < 64; o <<= 1) {
                        int v = __shfl_down(tot, o);
                        if (lane + o < 64) tot += v;
                    }
                    int cg = tot + carry;
                    s_cg[bin] = cg;
                    carry = __shfl(cg, 0);
                }
                if (lane == 0) s_cg[256] = 0;
            }
            __syncthreads();

            if (tid < 256) {
                if (s_cg[tid] >= k_rem && s_cg[tid + 1] < k_rem) s_sel = tid;
            }
            __syncthreads();

            const int bsel = s_sel;
            k_rem -= s_cg[bsel + 1];
            prefix |= (unsigned)bsel << sh;
            __syncthreads();
        }

        const float tval = __uint_as_float(prefix);   // exact k-th largest

        float sum = 0.f; int cgt = 0;
        for (int i = tid; i < P_; i += 1024) {
            float v = s_v[i];
            if (v > tval) { sum += v; cgt++; }
        }
        #pragma unroll
        for (int o = 32; o; o >>= 1) { sum += __shfl_xor(sum, o); cgt += __shfl_xor(cgt, o); }
        if (lane == 0) { s_rf[wv] = sum; s_rt[wv] = cgt; }
        __syncthreads();
        if (tid == 0) {
            float ssum = 0.f; int cc = 0;
            #pragma unroll
            for (int w = 0; w < 16; ++w) { ssum += s_rf[w]; cc += s_rt[w]; }
            hsum = ssum + (float)(k - cc) * tval;
        }
    }

    // ---- publish + last-block finalize (all blocks reach here) ----
    if (tid == 0) {
        float pt = 0.f, lt = 0.f;
        #pragma unroll
        for (int w = 0; w < 16; ++w) { pt += s_pa[w]; lt += s_la[w]; }
        atomicExch(&hard[b], hsum);
        atomicExch(&psum[b], pt);
        atomicExch(&lsum[b], lt);
        atomicExch(&npos[b], cp_tot);
        __threadfence();                // release before counter bump
        s_last = (atomicAdd(done_ctr, 1) == B_ - 1) ? 1 : 0;
    }
    __syncthreads();

    if (s_last && wv == 0) {            // wave 0 = lanes 0..63 = batches
        __threadfence();                // acquire side
        double h  = (double)atomicAdd(&hard[lane], 0.0f);
        double p  = (double)atomicAdd(&psum[lane], 0.0f);
        double l  = (double)atomicAdd(&lsum[lane], 0.0f);
        double np = (double)atomicAdd(&npos[lane], 0);
        #pragma unroll
        for (int o = 32; o; o >>= 1) {
            h += __shfl_xor(h, o); p += __shfl_xor(p, o);
            l += __shfl_xor(l, o); np += __shfl_xor(np, o);
        }
        if (lane == 0) {
            double conf_loss = (h + p) / np;
            double loc_loss  = l / fmax(np, 1.0);
            out[0] = (float)(conf_loss + 1.0 * loc_loss);
        }
    }
}

extern "C" void kernel_launch(void* const* d_in, const int* in_sizes, int n_in,
                              void* d_out, int out_size, void* d_ws, size_t ws_size,
                              hipStream_t stream) {
    const float* predicted_locs   = (const float*)d_in[0];
    const float* predicted_scores = (const float*)d_in[1];
    const float* boxes            = (const float*)d_in[2];
    const int*   labels           = (const int*)d_in[3];
    const float* priors           = (const float*)d_in[4];
    float* out = (float*)d_out;

    char* ws = (char*)d_ws;
    size_t off = 0;
    float* lse      = (float*)(ws + off); off += sizeof(float) * (size_t)B_ * P_;
    int*   tcls     = (int*)(ws + off);   off += sizeof(int)   * (size_t)B_ * P_;
    float* hard     = (float*)(ws + off); off += sizeof(float) * B_;
    float* psum     = (float*)(ws + off); off += sizeof(float) * B_;
    float* lsum     = (float*)(ws + off); off += sizeof(float) * B_;
    int*   npos     = (int*)(ws + off);   off += sizeof(int)   * B_;
    int*   done_ctr = (int*)(ws + off);   off += sizeof(int)   * 4;

    fused_assign_lse<<<AB_ + NCHUNKS, 256, 0, stream>>>(
        predicted_scores, boxes, labels, priors, lse, tcls, done_ctr);
    topk_kernel<<<B_, 1024, 0, stream>>>(
        predicted_scores, predicted_locs, lse, tcls,
        hard, psum, lsum, npos, done_ctr, out);
}

// Round 10
// 368.845 us; speedup vs baseline: 1.0728x; 1.0728x over previous
//
#include <hip/hip_runtime.h>
#include <math.h>

#define B_ 64
#define P_ 8732
#define M_ 16
#define C_ 81
#define THRESH 0.5f
#define EPS_ 1e-7f

#define AB_ 64                                  // assign-role blocks (one per batch)
#define ROWS_PER_CHUNK 64
#define NCHUNKS ((B_ * P_) / ROWS_PER_CHUNK)    // 8732
#define CHUNK_F4 (ROWS_PER_CHUNK * C_ / 4)      // 1296 = 5*256 + 16
#define GRID_CE 768                             // 256 CUs * 3 blocks/CU (LDS-bound)
#define GRAB 4                                  // chunks per steal (8732 = 2183*4)

// ---------------------------------------------------------------------------
// Kernel 0: zero the steal/done counters (workspace is poisoned every iter).
// ---------------------------------------------------------------------------
__global__ void init_kernel(int* __restrict__ ctrs) {
    if (threadIdx.x < 2) ctrs[threadIdx.x] = 0;   // [0]=chunk steal, [1]=done
}

// ---------------------------------------------------------------------------
// Kernel 1: persistent fused kernel.
//  - blocks 0..63 first run per-batch prior assignment (VALU-only, ~25 us,
//    hides under the BW-bound CE stream on the other blocks), then join CE.
//  - all 768 blocks then work-steal 4-chunk grabs of the CE-LSE stream:
//    double-buffered global_load_lds pipeline, one barrier per chunk, DMA
//    latency exposed only at grab boundaries (1/4 chunks).
// ---------------------------------------------------------------------------
__global__ __launch_bounds__(256, 3) void fused_assign_lse(
    const float* __restrict__ scores,   // [B,P,C]
    const float* __restrict__ boxes,    // [B,M,4] corner
    const int*   __restrict__ labels,   // [B,M]
    const float* __restrict__ priors,   // [P,4] cxcy
    float*       __restrict__ lse,      // [B*P]
    int*         __restrict__ tcls,     // [B*P]
    int*         __restrict__ ctrs)     // [0]=chunk steal
{
    __shared__ __attribute__((aligned(16))) float s_buf[2][ROWS_PER_CHUNK * C_];
    __shared__ float s_bx[M_][4];
    __shared__ float s_barea[M_];
    __shared__ int   s_lab[M_];
    __shared__ float s_wv4[M_][4];
    __shared__ int   s_wp4[M_][4];
    __shared__ int   s_tp[M_];
    __shared__ int   s_tn;
    __shared__ int   s_grab;

    const int tid  = threadIdx.x;
    const int lane = tid & 63;
    const int wv   = tid >> 6;                  // 4 waves

    if (blockIdx.x < AB_) {
        // =================== assign role (batch b) — verified R5 ===================
        const int b = blockIdx.x;

        if (tid < M_*4) ((float*)s_bx)[tid] = boxes[b*M_*4 + tid];
        if (tid < M_)   s_lab[tid] = labels[b*M_ + tid];
        __syncthreads();
        if (tid < M_)
            s_barea[tid] = (s_bx[tid][2]-s_bx[tid][0])*(s_bx[tid][3]-s_bx[tid][1]);
        __syncthreads();

        const float4* pri4 = (const float4*)priors;

        // ---- pass 1: per-object best prior (argmax over p, first-p wins) ----
        float bestv[M_]; int bestp[M_];
        #pragma unroll
        for (int m = 0; m < M_; ++m) { bestv[m] = -1.0f; bestp[m] = 0x7fffffff; }

        for (int p = tid; p < P_; p += 256) {
            float4 pc = pri4[p];
            float px1 = pc.x - pc.z*0.5f, py1 = pc.y - pc.w*0.5f;
            float px2 = pc.x + pc.z*0.5f, py2 = pc.y + pc.w*0.5f;
            float parea = (px2-px1)*(py2-py1);
            #pragma unroll
            for (int m = 0; m < M_; ++m) {
                float ix1 = fmaxf(s_bx[m][0], px1);
                float iy1 = fmaxf(s_bx[m][1], py1);
                float ix2 = fminf(s_bx[m][2], px2);
                float iy2 = fminf(s_bx[m][3], py2);
                float iw = fmaxf(ix2-ix1, 0.0f);
                float ih = fmaxf(iy2-iy1, 0.0f);
                float inter = iw*ih;
                float iou = inter / (s_barea[m] + parea - inter); // jaccard: no eps
                if (iou > bestv[m]) { bestv[m] = iou; bestp[m] = p; } // first p wins
            }
        }

        #pragma unroll
        for (int m = 0; m < M_; ++m) {
            float v = bestv[m]; int p = bestp[m];
            #pragma unroll
            for (int o = 32; o; o >>= 1) {
                float v2 = __shfl_xor(v, o);
                int   p2 = __shfl_xor(p, o);
                if (v2 > v || (v2 == v && p2 < p)) { v = v2; p = p2; }
            }
            if (lane == 0) { s_wv4[m][wv] = v; s_wp4[m][wv] = p; }
        }
        __syncthreads();

        // ---- serial: final reduce + faithful filtered-index override table ----
        if (tid == 0) {
            int cnt = 0;
            for (int m = 0; m < M_; ++m) {
                float v = s_wv4[m][0]; int p = s_wp4[m][0];
                #pragma unroll
                for (int w = 1; w < 4; ++w) {
                    float v2 = s_wv4[m][w]; int p2 = s_wp4[m][w];
                    if (v2 > v || (v2 == v && p2 < p)) { v = v2; p = p2; }
                }
                if (v > 0.0f) { s_tp[cnt] = p; cnt++; }  // entry e -> obj idx e
            }
            s_tn = cnt;
        }
        __syncthreads();

        const int tn = s_tn;

        // ---- pass 2: per-prior best (bitwise-identical recompute) + override ----
        for (int p = tid; p < P_; p += 256) {
            float4 pc = pri4[p];
            float px1 = pc.x - pc.z*0.5f, py1 = pc.y - pc.w*0.5f;
            float px2 = pc.x + pc.z*0.5f, py2 = pc.y + pc.w*0.5f;
            float parea = (px2-px1)*(py2-py1);
            float bv = -1.0f; int bm = 0;
            #pragma unroll
            for (int m = 0; m < M_; ++m) {
                float ix1 = fmaxf(s_bx[m][0], px1);
                float iy1 = fmaxf(s_bx[m][1], py1);
                float ix2 = fminf(s_bx[m][2], px2);
                float iy2 = fminf(s_bx[m][3], py2);
                float iw = fmaxf(ix2-ix1, 0.0f);
                float ih = fmaxf(iy2-iy1, 0.0f);
                float inter = iw*ih;
                float iou = inter / (s_barea[m] + parea - inter);
                if (iou > bv) { bv = iou; bm = m; }       // first-max (m asc)
            }
            int ovr = -1;
            for (int e = 0; e < tn; ++e)
                if (s_tp[e] == p) ovr = e;                // last valid m wins
            int tc = (ovr >= 0) ? s_lab[ovr]              // ovl forced to 1.0
                                : ((bv < THRESH) ? 0 : s_lab[bm]);
            tcls[(size_t)b*P_ + p] = tc;
        }
        __syncthreads();
    }

    // =================== persistent CE-LSE role (all blocks) ===================
    const int s  = lane & 3;                    // sub-lane within row quad
    const int rl = (lane >> 2) + wv * 16;       // row within chunk, 0..63
    const int cnt   = (s == 0) ? 21 : 20;
    const int cbase = (s == 0) ? 0  : (1 + 20 * s);     // 0,21,41,61
    const float4* sc4 = (const float4*)scores;

    if (tid == 0) s_grab = atomicAdd(&ctrs[0], GRAB);
    __syncthreads();
    int g = s_grab;
    int cur = 0;

    while (g < NCHUNKS) {
        const int gend = min(g + GRAB, NCHUNKS);

        // grab prologue: full stage of chunk g into buf[cur] (latency exposed
        // once per grab; amortized over GRAB chunks)
        {
            const float4* src4 = sc4 + (size_t)g * CHUNK_F4;
            float4*       dst4 = (float4*)s_buf[cur];
            #pragma unroll
            for (int k = 0; k < 5; ++k) {
                __builtin_amdgcn_global_load_lds(
                    (const __attribute__((address_space(1))) void*)(src4 + k*256 + tid),
                    (__attribute__((address_space(3))) void*)(dst4 + k*256 + wv*64),
                    16, 0, 0);
            }
            if (tid < 16) dst4[1280 + tid] = src4[1280 + tid];
        }
        __syncthreads();                        // drains chunk-g DMA

        for (int c = g; ; ) {
            const int  cn       = c + 1;
            const bool boundary = (cn >= gend);     // block-uniform
            float4 tail;

            if (!boundary) {
                // fire-and-forget prefetch of chunk cn into the other buffer
                const float4* src4 = sc4 + (size_t)cn * CHUNK_F4;
                float4*       dst4 = (float4*)s_buf[cur ^ 1];
                #pragma unroll
                for (int k = 0; k < 5; ++k) {
                    __builtin_amdgcn_global_load_lds(
                        (const __attribute__((address_space(1))) void*)(src4 + k*256 + tid),
                        (__attribute__((address_space(3))) void*)(dst4 + k*256 + wv*64),
                        16, 0, 0);
                }
                if (tid < 16) tail = src4[1280 + tid];   // async load to reg
            } else {
                if (tid == 0) s_grab = atomicAdd(&ctrs[0], GRAB);  // overlap steal
            }

            // ---- compute chunk c from s_buf[cur] ----
            const float* rowp = &s_buf[cur][rl * C_ + cbase];
            float x[21];
            float mx = -INFINITY;
            #pragma unroll
            for (int k = 0; k < 21; ++k) {
                if (k < cnt) { x[k] = rowp[k]; mx = fmaxf(mx, x[k]); }
                else x[k] = -INFINITY;
            }
            mx = fmaxf(mx, __shfl_xor(mx, 1));
            mx = fmaxf(mx, __shfl_xor(mx, 2));

            float e = 0.f;
            #pragma unroll
            for (int k = 0; k < 21; ++k) e += __expf(x[k] - mx);  // exp(-inf)=0 pad
            e += __shfl_xor(e, 1);
            e += __shfl_xor(e, 2);

            if (s == 0)
                lse[(size_t)c * ROWS_PER_CHUNK + rl] = mx + __logf(e);

            // tail write for prefetch (vmcnt wait hidden behind compute)
            if (!boundary && tid < 16)
                ((float4*)s_buf[cur ^ 1])[1280 + tid] = tail;

            __syncthreads();   // drains prefetch DMA; makes s_grab visible
            if (boundary) break;
            c = cn; cur ^= 1;
        }
        g = s_grab;            // next grab (buf[cur] reusable: all waves past barrier)
    }
}

// ---------------------------------------------------------------------------
// Kernel 2: per-batch conf reconstruction (lse - gathered x[t]) + positives
// accounting + exact top-k radix select + last-block scalar finalize.
// (verified R5; only ctrs indexing changed)
// ---------------------------------------------------------------------------
__global__ __launch_bounds__(1024) void topk_kernel(
    const float* __restrict__ scores,   // [B,P,C]
    const float* __restrict__ locs,     // [B,P,4]
    const float* __restrict__ lse,      // [B*P]
    const int*   __restrict__ tcls,     // [B*P]
    float*       __restrict__ hard,     // [B]
    float*       __restrict__ psum,     // [B]
    float*       __restrict__ lsum,     // [B]
    int*         __restrict__ npos,     // [B]
    int*         __restrict__ ctrs,     // [1]=done
    float*       __restrict__ out)      // [1]
{
    const int b = blockIdx.x;
    const int tid = threadIdx.x;
    const int lane = tid & 63;
    const int wv = tid >> 6;

    __shared__ float s_v[P_];           // 34928 B
    __shared__ int   s_hist[16][256];   // 16384 B
    __shared__ int   s_cg[257];
    __shared__ int   s_sel;
    __shared__ int   s_ct[16];
    __shared__ float s_pa[16];
    __shared__ float s_la[16];
    __shared__ int   s_rt[16];
    __shared__ float s_rf[16];
    __shared__ int   s_last;

    const size_t base = (size_t)b * P_;

    // ---- load pass: conf = lse - x[t]; build s_v; count/sum positives ----
    float p_acc = 0.f, l_acc = 0.f; int cpos = 0;
    for (int i = tid; i < P_; i += 1024) {
        const int t = tcls[base + i];
        const float conf = lse[base + i] - scores[(base + i) * C_ + t];
        float v;
        if (t > 0) {
            v = 0.f;
            cpos++;
            p_acc += conf;
            // DIoU(box, box): inter_diag == 0; enclosing box == box
            float4 bx = ((const float4*)locs)[base + i];
            float w = bx.z - bx.x, h = bx.w - bx.y;
            float iw = fmaxf(w, 0.f), ih = fmaxf(h, 0.f);
            float inter = iw * ih;
            float area  = w * h;
            float iou   = inter / (area + area - inter + EPS_);
            float diou  = fminf(fmaxf(iou, -1.f), 1.f);
            l_acc += 1.f - diou;
        } else {
            v = fmaxf(conf, 0.f);       // order-monotonic float bits
        }
        s_v[i] = v;
    }

    #pragma unroll
    for (int o = 32; o; o >>= 1) {
        cpos  += __shfl_xor(cpos, o);
        p_acc += __shfl_xor(p_acc, o);
        l_acc += __shfl_xor(l_acc, o);
    }
    if (lane == 0) { s_ct[wv] = cpos; s_pa[wv] = p_acc; s_la[wv] = l_acc; }
    __syncthreads();                    // also covers s_v

    int cp_tot = 0;
    #pragma unroll
    for (int w = 0; w < 16; ++w) cp_tot += s_ct[w];   // uniform across block
    int k = 3 * cp_tot;
    if (k > P_) k = P_;

    float hsum = 0.f;                   // tid 0's value is the one that counts
    if (k > 0) {                        // block-uniform branch
        const unsigned masks[4]  = {0u, 0xFF800000u, 0xFFFF8000u, 0xFFFFFF80u};
        const int      shifts[4] = {23, 15, 7, 0};

        unsigned prefix = 0u;
        int k_rem = k;

        for (int rd = 0; rd < 4; ++rd) {
            const unsigned hm = masks[rd];
            const int sh = shifts[rd];

            ((int*)s_hist)[tid] = 0;
            ((int*)s_hist)[tid + 1024] = 0;
            ((int*)s_hist)[tid + 2048] = 0;
            ((int*)s_hist)[tid + 3072] = 0;
            __syncthreads();

            for (int i = tid; i < P_; i += 1024) {
                unsigned u = __float_as_uint(s_v[i]);
                if ((u & hm) == prefix)
                    atomicAdd(&s_hist[wv][(u >> sh) & 0xFF], 1);
            }
            __syncthreads();

            if (wv == 0) {
                int carry = 0;
                for (int cbin = 3; cbin >= 0; --cbin) {
                    int bin = cbin * 64 + lane;
                    int tot = 0;
                    #pragma unroll
                    for (int w = 0; w < 16; ++w) tot += s_hist[w][bin];
                    #pragma unroll
                    for (int o = 1; o < 64; o <<= 1) {
                        int v = __shfl_down(tot, o);
                        if (lane + o < 64) tot += v;
                    }
                    int cg = tot + carry;
                    s_cg[bin] = cg;
                    carry = __shfl(cg, 0);
                }
                if (lane == 0) s_cg[256] = 0;
            }
            __syncthreads();

            if (tid < 256) {
                if (s_cg[tid] >= k_rem && s_cg[tid + 1] < k_rem) s_sel = tid;
            }
            __syncthreads();

            const int bsel = s_sel;
            k_rem -= s_cg[bsel + 1];
            prefix |= (unsigned)bsel << sh;
            __syncthreads();
        }

        const float tval = __uint_as_float(prefix);   // exact k-th largest

        float sum = 0.f; int cgt = 0;
        for (int i = tid; i < P_; i += 1024) {
            float v = s_v[i];
            if (v > tval) { sum += v; cgt++; }
        }
        #pragma unroll
        for (int o = 32; o; o >>= 1) { sum += __shfl_xor(sum, o); cgt += __shfl_xor(cgt, o); }
        if (lane == 0) { s_rf[wv] = sum; s_rt[wv] = cgt; }
        __syncthreads();
        if (tid == 0) {
            float ssum = 0.f; int cc = 0;
            #pragma unroll
            for (int w = 0; w < 16; ++w) { ssum += s_rf[w]; cc += s_rt[w]; }
            hsum = ssum + (float)(k - cc) * tval;
        }
    }

    // ---- publish + last-block finalize (all blocks reach here) ----
    if (tid == 0) {
        float pt = 0.f, lt = 0.f;
        #pragma unroll
        for (int w = 0; w < 16; ++w) { pt += s_pa[w]; lt += s_la[w]; }
        atomicExch(&hard[b], hsum);
        atomicExch(&psum[b], pt);
        atomicExch(&lsum[b], lt);
        atomicExch(&npos[b], cp_tot);
        __threadfence();                // release before counter bump
        s_last = (atomicAdd(&ctrs[1], 1) == B_ - 1) ? 1 : 0;
    }
    __syncthreads();

    if (s_last && wv == 0) {            // wave 0 = lanes 0..63 = batches
        __threadfence();                // acquire side
        double h  = (double)atomicAdd(&hard[lane], 0.0f);
        double p  = (double)atomicAdd(&psum[lane], 0.0f);
        double l  = (double)atomicAdd(&lsum[lane], 0.0f);
        double np = (double)atomicAdd(&npos[lane], 0);
        #pragma unroll
        for (int o = 32; o; o >>= 1) {
            h += __shfl_xor(h, o); p += __shfl_xor(p, o);
            l += __shfl_xor(l, o); np += __shfl_xor(np, o);
        }
        if (lane == 0) {
            double conf_loss = (h + p) / np;
            double loc_loss  = l / fmax(np, 1.0);
            out[0] = (float)(conf_loss + 1.0 * loc_loss);
        }
    }
}

extern "C" void kernel_launch(void* const* d_in, const int* in_sizes, int n_in,
                              void* d_out, int out_size, void* d_ws, size_t ws_size,
                              hipStream_t stream) {
    const float* predicted_locs   = (const float*)d_in[0];
    const float* predicted_scores = (const float*)d_in[1];
    const float* boxes            = (const float*)d_in[2];
    const int*   labels           = (const int*)d_in[3];
    const float* priors           = (const float*)d_in[4];
    float* out = (float*)d_out;

    char* ws = (char*)d_ws;
    size_t off = 0;
    float* lse      = (float*)(ws + off); off += sizeof(float) * (size_t)B_ * P_;
    int*   tcls     = (int*)(ws + off);   off += sizeof(int)   * (size_t)B_ * P_;
    float* hard     = (float*)(ws + off); off += sizeof(float) * B_;
    float* psum     = (float*)(ws + off); off += sizeof(float) * B_;
    float* lsum     = (float*)(ws + off); off += sizeof(float) * B_;
    int*   npos     = (int*)(ws + off);   off += sizeof(int)   * B_;
    int*   ctrs     = (int*)(ws + off);   off += sizeof(int)   * 4;

    init_kernel<<<1, 64, 0, stream>>>(ctrs);
    fused_assign_lse<<<GRID_CE, 256, 0, stream>>>(
        predicted_scores, boxes, labels, priors, lse, tcls, ctrs);
    topk_kernel<<<B_, 1024, 0, stream>>>(
        predicted_scores, predicted_locs, lse, tcls,
        hard, psum, lsum, npos, ctrs, out);
}